// Round 5
// baseline (252.363 us; speedup 1.0000x reference)
//
#include <hip/hip_runtime.h>
#include <hip/hip_bf16.h>
#include <stdint.h>

typedef __bf16 bf16;
typedef bf16 bf16x4 __attribute__((ext_vector_type(4)));
typedef bf16 bf16x8 __attribute__((ext_vector_type(8)));
typedef float f32x4 __attribute__((ext_vector_type(4)));
typedef float fv4 __attribute__((ext_vector_type(4)));   // native clang vector for nontemporal builtins

#define FIN   128
#define FOUT  128
#define FANIN 640
#define BM    64      // rows per block; 16 rows per wave = one MFMA A-fragment row-group
#define BK    64      // K per chunk; 10 chunks cover K=640

__device__ __forceinline__ void async16(const void* g, void* l) {
    __builtin_amdgcn_global_load_lds((const __attribute__((address_space(1))) void*)g,
                                     (__attribute__((address_space(3))) void*)l,
                                     16, 0, 0);
}

// ---------------- convert fp32 -> bf16 (x and W), non-temporal reads ----------------
__global__ __launch_bounds__(256)
void convert_kernel(const float* __restrict__ x, const float* __restrict__ W,
                    bf16* __restrict__ xb, bf16* __restrict__ wb,
                    long nx4, long ntot4)
{
    long i = (long)blockIdx.x * 256 + threadIdx.x;
    if (i >= ntot4) return;
    fv4 v;
    bf16* dst;
    if (i < nx4) { v = __builtin_nontemporal_load((const fv4*)x + i); dst = xb + i * 4; }
    else         { long k = i - nx4;
                   v = __builtin_nontemporal_load((const fv4*)W + k); dst = wb + k * 4; }
    bf16x4 h = { (bf16)v.x, (bf16)v.y, (bf16)v.z, (bf16)v.w };
    *(bf16x4*)dst = h;
}

// ---------------- gather-GEMM: A direct-to-register, B double-buffered LDS ----------------
// Block = 64 rows x 128 cols. Wave w owns rows [w*16, w*16+16): A fragment row = lane&15,
// so the gathered A fragment is ONE global_load_dwordx4 per K-step — no LDS round trip,
// prefetched one chunk ahead (plain VGPR loads ride across barriers).
// B (W) is double-buffered in LDS (2 x 16KB), staged by async16 with XOR swizzle,
// ONE barrier per chunk; everything the barrier drains is consumed right after it.
__global__ __launch_bounds__(256, 4)
void mcc_mfma(const bf16* __restrict__ xb, const int* __restrict__ nbr,
              const bf16* __restrict__ wb, const float* __restrict__ bias,
              float* __restrict__ out, int N)
{
    __shared__ __align__(16) bf16 Bsm[2][FOUT][BK];   // 32 KB

    const int tid  = threadIdx.x;
    const int wave = tid >> 6;
    const int lane = tid & 63;
    const int quad = lane >> 4;
    const int l16  = lane & 15;
    const int m0   = blockIdx.x * BM;

    const int r8 = lane >> 3;        // B staging: row within 8-row group
    const int c8 = lane & 7;         // B staging: 16B chunk within 128B row

    // gather row ids: this lane's output row (l16 within the wave's 16-row band)
    int row = m0 + wave * 16 + l16;
    row = row < N ? row : N - 1;
    int gsel[5];
    gsel[0] = row;
    {
        int4 nv = ((const int4*)nbr)[row];   // 16B per lane; quads redundant -> L2 broadcast
        gsel[1] = nv.x; gsel[2] = nv.y; gsel[3] = nv.z; gsel[4] = nv.w;
    }

    f32x4 acc[8] = {};
    bf16x8 a_cur[2], a_nxt[2];

    // chunk c (0..9): gather slot j = c>>1, 128B half h = c&1; global k-byte base = c*128
    auto loadA = [&](int c, bf16x8* a) {
        const char* gp = (const char*)xb + ((long)gsel[c >> 1] << 8) + (c & 1) * 128 + quad * 16;
        a[0] = *(const bf16x8*)(gp);        // k = c*64 + 0..31 slice for this quad
        a[1] = *(const bf16x8*)(gp + 64);   // k = c*64 + 32..63
    };
    auto stageB = [&](int c, int buf) {
        #pragma unroll
        for (int i = 0; i < 4; ++i) {
            int brow = wave * 32 + i * 8;   // 8 W-rows (1KB) per async16
            const char* gp = (const char*)wb + (long)(brow + r8) * (FANIN * 2)
                             + c * 128 + ((c8 ^ r8) << 4);
            async16(gp, &Bsm[buf][brow][0]);
        }
    };

    stageB(0, 0);
    loadA(0, a_cur);

    #pragma unroll
    for (int c = 0; c < 10; ++c) {
        __syncthreads();                          // B_c ready (drains A_c too — needed now)
        if (c < 9) {
            stageB(c + 1, (c + 1) & 1);           // in flight during this chunk's MFMAs
            loadA(c + 1, a_nxt);
        }
        #pragma unroll
        for (int s = 0; s < 2; ++s) {
            #pragma unroll
            for (int ni = 0; ni < 8; ++ni) {
                int col = ni * 16 + l16;
                bf16x8 b = *(const bf16x8*)&Bsm[c & 1][col][(((s * 4 + quad) ^ (l16 & 7)) << 3)];
                acc[ni] = __builtin_amdgcn_mfma_f32_16x16x32_bf16(a_cur[s], b, acc[ni], 0, 0, 0);
            }
        }
        a_cur[0] = a_nxt[0];
        a_cur[1] = a_nxt[1];
    }

    // ---- epilogue: C layout col=lane&15, row=quad*4+reg; non-temporal stores ----
    #pragma unroll
    for (int ni = 0; ni < 8; ++ni) {
        int n = ni * 16 + l16;
        float bv = bias[n];
        #pragma unroll
        for (int r = 0; r < 4; ++r) {
            int orow = m0 + wave * 16 + quad * 4 + r;
            if (orow < N)
                __builtin_nontemporal_store(acc[ni][r] + bv, &out[(long)orow * FOUT + n]);
        }
    }
}

// ---------------- round-1 fallback (used only if ws_size too small) ----------------
#define FBM 64
#define LDA 136
__global__ __launch_bounds__(256)
void mcc_fallback(const float* __restrict__ x, const int* __restrict__ nbr,
                  const float* __restrict__ W, const float* __restrict__ bias,
                  float* __restrict__ out, int N)
{
    __shared__ __align__(16) bf16 As[FBM][LDA];
    __shared__ __align__(16) bf16 Bs[FOUT][LDA];
    const int tid = threadIdx.x;
    const int m0 = blockIdx.x * FBM;
    const int wave = tid >> 6, lane = tid & 63, quad = lane >> 4, l16 = lane & 15;
    f32x4 acc[8] = {};
    const int arow = tid >> 2, asub = tid & 3, brow = tid >> 1, bhalf = tid & 1;
    for (int j = 0; j < 5; ++j) {
        {
            const float4* src = (const float4*)(W + (long)brow * FANIN + j * FIN + bhalf * 64);
            bf16* dst = &Bs[brow][bhalf * 64];
            #pragma unroll
            for (int i = 0; i < 16; ++i) {
                float4 v = src[i];
                dst[i*4+0]=(bf16)v.x; dst[i*4+1]=(bf16)v.y; dst[i*4+2]=(bf16)v.z; dst[i*4+3]=(bf16)v.w;
            }
        }
        {
            int node = m0 + arow; int nc = node < N ? node : N - 1;
            long long g = (j == 0) ? (long long)nc : (long long)nbr[(long long)nc * 4 + (j - 1)];
            const float4* src = (const float4*)(x + g * FIN);
            #pragma unroll
            for (int i = 0; i < 8; ++i) {
                int c4 = asub + i * 4;
                float4 v = src[c4];
                bf16* dst = &As[arow][c4 * 4];
                dst[0]=(bf16)v.x; dst[1]=(bf16)v.y; dst[2]=(bf16)v.z; dst[3]=(bf16)v.w;
            }
        }
        __syncthreads();
        #pragma unroll
        for (int kk = 0; kk < 4; ++kk) {
            bf16x8 a = *(const bf16x8*)&As[wave * 16 + l16][kk * 32 + quad * 8];
            #pragma unroll
            for (int nt = 0; nt < 8; ++nt) {
                bf16x8 b = *(const bf16x8*)&Bs[nt * 16 + l16][kk * 32 + quad * 8];
                acc[nt] = __builtin_amdgcn_mfma_f32_16x16x32_bf16(a, b, acc[nt], 0, 0, 0);
            }
        }
        __syncthreads();
    }
    const int m_local = wave * 16 + quad * 4;
    #pragma unroll
    for (int nt = 0; nt < 8; ++nt) {
        int n = nt * 16 + l16;
        float bvv = bias[n];
        #pragma unroll
        for (int r = 0; r < 4; ++r) {
            int node = m0 + m_local + r;
            if (node < N) out[(long)node * FOUT + n] = acc[nt][r] + bvv;
        }
    }
}

extern "C" void kernel_launch(void* const* d_in, const int* in_sizes, int n_in,
                              void* d_out, int out_size, void* d_ws, size_t ws_size,
                              hipStream_t stream) {
    const float* x    = (const float*)d_in[0];
    const int*   nbr  = (const int*)d_in[1];
    const float* W    = (const float*)d_in[2];
    const float* bias = (const float*)d_in[3];
    float* out = (float*)d_out;

    int N = in_sizes[0] / FIN;                              // 200000
    size_t xb_bytes = (size_t)N * FIN * sizeof(bf16);       // 51.2 MB
    size_t wb_bytes = (size_t)FOUT * FANIN * sizeof(bf16);  // 160 KB

    if (ws_size >= xb_bytes + wb_bytes) {
        bf16* xb = (bf16*)d_ws;
        bf16* wb = (bf16*)((char*)d_ws + xb_bytes);
        long nx4   = (long)N * FIN / 4;
        long ntot4 = nx4 + (long)FOUT * FANIN / 4;
        int cgrid = (int)((ntot4 + 255) / 256);
        convert_kernel<<<cgrid, 256, 0, stream>>>(x, W, xb, wb, nx4, ntot4);
        int grid = (N + BM - 1) / BM;                       // 3125
        mcc_mfma<<<grid, 256, 0, stream>>>(xb, nbr, wb, bias, out, N);
    } else {
        int grid = (N + FBM - 1) / FBM;
        mcc_fallback<<<grid, 256, 0, stream>>>(x, nbr, W, bias, out, N);
    }
}